// Round 7
// baseline (104.047 us; speedup 1.0000x reference)
//
#include <hip/hip_runtime.h>

namespace {

constexpr int NQ = 10;

struct cplx { float re, im; };

__device__ __forceinline__ cplx cmul(cplx a, cplx b) {
  return cplx{ fmaf(a.re, b.re, -a.im * b.im), fmaf(a.re, b.im, a.im * b.re) };
}
// u*a + v*b (complex), 8 scalar FMA
__device__ __forceinline__ cplx cmadd2(cplx u, cplx a, cplx v, cplx b) {
  cplx r;
  r.re = fmaf(u.re, a.re, fmaf(-u.im, a.im, fmaf(v.re, b.re, -v.im * b.im)));
  r.im = fmaf(u.re, a.im, fmaf( u.im, a.re, fmaf(v.re, b.im,  v.im * b.re)));
  return r;
}
__device__ __forceinline__ cplx csel(bool c, cplx x, cplx y) {
  return cplx{ c ? x.re : y.re, c ? x.im : y.im };
}

__device__ __forceinline__ float fast_tanh(float x) {
  float xc = fminf(fmaxf(x, -10.f), 10.f);
  float e = __expf(2.f * xc);
  return __fdividef(e - 1.f, e + 1.f);
}

// ---- cross-lane primitives ----
__device__ __forceinline__ float rdlane(float v, int l) {
  return __int_as_float(__builtin_amdgcn_readlane(__float_as_int(v), l));
}
// DPP: quad_perm xor1=0xB1 xor2=0x4E xor3=0x1B; row_ror:8=0x128 (xor8);
// row_half_mirror=0x141 (xor7)
template<int CTRL>
__device__ __forceinline__ float dppf(float v) {
  return __int_as_float(__builtin_amdgcn_update_dpp(0, __float_as_int(v), CTRL, 0xF, 0xF, true));
}
template<int PAT>   // ds_swizzle BitMode: (xor<<10)|(or<<5)|and
__device__ __forceinline__ float swzf(float v) {
  return __int_as_float(__builtin_amdgcn_ds_swizzle(__float_as_int(v), PAT));
}
__device__ __forceinline__ float bperm(int addr, float v) {
  return __int_as_float(__builtin_amdgcn_ds_bpermute(addr, __float_as_int(v)));
}

// ---- per-lane Rot matrices (lane g holds gate g), broadcast by readlane ----
// readlane accepts a runtime (SGPR) lane index -> rolled loops stay rolled.
struct Umat { float r00,i00,r01,i01,r10,i10,r11,i11; };
__device__ __forceinline__ void getU(const Umat& m, int g,
                                     cplx& u00, cplx& u01, cplx& u10, cplx& u11) {
  u00 = cplx{rdlane(m.r00, g), rdlane(m.i00, g)};
  u01 = cplx{rdlane(m.r01, g), rdlane(m.i01, g)};
  u10 = cplx{rdlane(m.r10, g), rdlane(m.i10, g)};
  u11 = cplx{rdlane(m.r11, g), rdlane(m.i11, g)};
}

// ---- identity-layout lane gate (bit 9..4 -> lane bit 5..0), runtime g & kb ----
// batched gather: issue all 32 bpermutes, then consume (one DS latency per gate)
__device__ __forceinline__ void lane_gate(cplx (&amp)[16], int lane, const Umat& m,
                                          int g, int kb) {
  cplx u00, u01, u10, u11; getU(m, g, u00, u01, u10, u11);
  bool hi = ((lane >> kb) & 1) != 0;
  cplx cA = csel(hi, u11, u00), cB = csel(hi, u10, u01);
  const int addr = (lane ^ (1 << kb)) << 2;
  float ore[16], oim[16];
  #pragma unroll
  for (int t = 0; t < 16; ++t) { ore[t] = bperm(addr, amp[t].re); oim[t] = bperm(addr, amp[t].im); }
  #pragma unroll
  for (int t = 0; t < 16; ++t) amp[t] = cmadd2(cA, amp[t], cB, cplx{ore[t], oim[t]});
}

// ---- identity-layout local gate (bit 3..0), lane-independent ----
template<int BBIT>
__device__ __forceinline__ void local_gate(cplx (&amp)[16], const Umat& m, int g) {
  cplx u00, u01, u10, u11; getU(m, g, u00, u01, u10, u11);
  #pragma unroll
  for (int t0 = 0; t0 < 16; ++t0) {
    if (t0 & BBIT) continue;
    const int t1 = t0 | BBIT;
    cplx a0 = amp[t0], a1 = amp[t1];
    amp[t0] = cmadd2(u00, a0, u01, a1);
    amp[t1] = cmadd2(u10, a0, u11, a1);
  }
}

// ---- physical CNOT chain (9,8)(8,7)...(1,0), all 3 steps fused ----
// lane part: src = lane ^ (lane>>1)  (verified R1); (4,3): ctrl = lane bit0
// swaps t <-> t|8; local (3..0): t -> t^(t>>1). Combined into one reg permute.
__device__ __forceinline__ void chain(cplx (&amp)[16], int lane) {
  const int addr = ((lane ^ (lane >> 1)) & 63) << 2;
  float ore[16], oim[16];
  #pragma unroll
  for (int t = 0; t < 16; ++t) { ore[t] = bperm(addr, amp[t].re); oim[t] = bperm(addr, amp[t].im); }
  const bool ctrl = (lane & 1) != 0;
  #pragma unroll
  for (int t = 0; t < 16; ++t) {
    const int ta = t ^ (t >> 1);
    const int tb = ta ^ 8;
    amp[t].re = ctrl ? ore[tb] : ore[ta];
    amp[t].im = ctrl ? oim[tb] : oim[ta];
  }
}

// 6-stage lane-space Walsh-Hadamard butterfly: lane L ends with sum_l v_l*(-1)^popc(l&L)
__device__ __forceinline__ float wht6(float v, float s1, float s2, float s4,
                                      float s8, float s16, float s32) {
  float o;
  o = dppf<0xB1>(v);               v = fmaf(s1,  v, o);   // xor1
  o = dppf<0x4E>(v);               v = fmaf(s2,  v, o);   // xor2
  o = dppf<0x1B>(dppf<0x141>(v));  v = fmaf(s4,  v, o);   // xor4 = xor7 o xor3
  o = dppf<0x128>(v);              v = fmaf(s8,  v, o);   // xor8
  o = swzf<0x401F>(v);             v = fmaf(s16, v, o);   // xor16 (DS swizzle)
  o = __shfl_xor(v, 32);           v = fmaf(s32, v, o);   // xor32 (DS bpermute)
  return v;
}

__global__ __launch_bounds__(256, 4)
void qgan_kernel(const float* __restrict__ z, const float* __restrict__ wts,
                 const float* __restrict__ W1, const float* __restrict__ b1,
                 const float* __restrict__ W2, const float* __restrict__ b2,
                 const float* __restrict__ W3, const float* __restrict__ b3,
                 float* __restrict__ out, int B)
{
  const int tid  = blockIdx.x * 256 + threadIdx.x;
  const int lane = threadIdx.x & 63;
  const int wv   = __builtin_amdgcn_readfirstlane(tid >> 6);   // one elem per wave
  if (wv >= B) return;

  // ---- 30 Rot matrices lane-parallel (lane g -> gate g) ----
  Umat m;
  {
    int g = (lane < 30) ? lane : 0;
    float wa = wts[g * 3 + 0], wb = wts[g * 3 + 1], wc = wts[g * 3 + 2];
    float al = 0.5f * (wa + wc), be = 0.5f * (wa - wc), hb = 0.5f * wb;
    float ca = __cosf(al),  sa = __sinf(al);
    float cbe = __cosf(be), sbe = __sinf(be);
    float cb = __cosf(hb),  sb = __sinf(hb);
    m.r00 =  cb * ca;  m.i00 = -cb * sa;
    m.r01 = -sb * cbe; m.i01 = -sb * sbe;
    m.r10 =  sb * cbe; m.i10 = -sb * sbe;
    m.r11 =  cb * ca;  m.i11 =  cb * sa;
  }

  cplx u00, u01, u10, u11;
  const float* zp = z + wv * NQ;           // wave-uniform -> scalar loads

  // ---- init: RY product state fused with layer-0 1q gates (identity layout) ----
  cplx laneF = {1.f, 0.f};
  #pragma unroll
  for (int q = 0; q < 6; ++q) {            // wires 0..5 -> lane bits 5..0
    float zz = fminf(fmaxf(zp[q], -1.f), 1.f);
    float c0 = __cosf(0.5f * zz), s0 = __sinf(0.5f * zz);
    getU(m, q, u00, u01, u10, u11);
    cplx va = { fmaf(u00.re, c0, u01.re * s0), fmaf(u00.im, c0, u01.im * s0) };
    cplx vb = { fmaf(u10.re, c0, u11.re * s0), fmaf(u10.im, c0, u11.im * s0) };
    cplx f = csel((lane >> (5 - q)) & 1, vb, va);
    laneF = (q == 0) ? f : cmul(laneF, f);
  }
  cplx va_[4], vb_[4];                     // wires 6..9 -> local bits 3..0
  #pragma unroll
  for (int q = 6; q < 10; ++q) {
    float zz = fminf(fmaxf(zp[q], -1.f), 1.f);
    float c0 = __cosf(0.5f * zz), s0 = __sinf(0.5f * zz);
    getU(m, q, u00, u01, u10, u11);
    va_[q - 6] = { fmaf(u00.re, c0, u01.re * s0), fmaf(u00.im, c0, u01.im * s0) };
    vb_[q - 6] = { fmaf(u10.re, c0, u11.re * s0), fmaf(u10.im, c0, u11.im * s0) };
  }

  cplx amp[16];
  {
    cplx P2[4];
    P2[0] = cmul(va_[2], va_[3]);
    P2[1] = cmul(va_[2], vb_[3]);
    P2[2] = cmul(vb_[2], va_[3]);
    P2[3] = cmul(vb_[2], vb_[3]);
    cplx g0 = cmul(laneF, va_[0]);         // wire6 = bit3
    cplx g1 = cmul(laneF, vb_[0]);
    #pragma unroll
    for (int t = 0; t < 16; ++t) {
      cplx t7 = ((t >> 2) & 1) ? vb_[1] : va_[1];
      cplx tt = cmul(t7, P2[t & 3]);
      amp[t] = cmul(((t >> 3) & 1) ? g1 : g0, tt);
    }
  }

  // ---- layers 1,2 in identity layout; physical chain after each layer-block.
  //      Single rolled loop -> one code instance of lane_gate / local set / chain.
  #pragma unroll 1
  for (int l = 0; l < 3; ++l) {
    if (l) {
      const int gbase = 10 * l;
      #pragma unroll 1
      for (int q = 0; q < 6; ++q)
        lane_gate(amp, lane, m, gbase + q, 5 - q);   // wires 0..5 -> lane bits 5..0
      local_gate<8>(amp, m, gbase + 6);              // wire6 -> bit3
      local_gate<4>(amp, m, gbase + 7);
      local_gate<2>(amp, m, gbase + 8);
      local_gate<1>(amp, m, gbase + 9);
    }
    chain(amp, lane);                                // after layer 0 (init), 1, 2
  }

  // ---- measurement in identity layout (all chains physical): plain Z parities ----
  float p[16];
  #pragma unroll
  for (int t = 0; t < 16; ++t)
    p[t] = fmaf(amp[t].re, amp[t].re, amp[t].im * amp[t].im);

  // local 4-bit WHT: p[mu] := sum_t p0[t] (-1)^popc(t&mu)
  #pragma unroll
  for (int k = 1; k <= 8; k <<= 1) {
    #pragma unroll
    for (int t = 0; t < 16; ++t) {
      if (t & k) continue;
      float a = p[t], b = p[t | k];
      p[t] = a + b; p[t | k] = a - b;
    }
  }

  float s1  = (lane & 1)  ? -1.f : 1.f;
  float s2  = (lane & 2)  ? -1.f : 1.f;
  float s4  = (lane & 4)  ? -1.f : 1.f;
  float s8  = (lane & 8)  ? -1.f : 1.f;
  float s16 = (lane & 16) ? -1.f : 1.f;
  float s32 = (lane & 32) ? -1.f : 1.f;
  float B0 = wht6(p[0], s1,s2,s4,s8,s16,s32);
  float B8 = wht6(p[8], s1,s2,s4,s8,s16,s32);
  float B4 = wht6(p[4], s1,s2,s4,s8,s16,s32);
  float B2 = wht6(p[2], s1,s2,s4,s8,s16,s32);
  float B1 = wht6(p[1], s1,s2,s4,s8,s16,s32);

  // feat(wire w) = WHT point (lane-mask, local-mask); bit b=9-w.
  float feats[10];
  feats[0] = rdlane(B0, 0x20); feats[1] = rdlane(B0, 0x10);
  feats[2] = rdlane(B0, 0x08); feats[3] = rdlane(B0, 0x04);
  feats[4] = rdlane(B0, 0x02); feats[5] = rdlane(B0, 0x01);
  feats[6] = rdlane(B8, 0);    feats[7] = rdlane(B4, 0);
  feats[8] = rdlane(B2, 0);    feats[9] = rdlane(B1, 0);

  // ---- MLP: 10->32 tanh ->16 tanh ->1 ; sigmoid*0.2-0.1 == 0.1*tanh(raw/2) ----
  // weights loaded late (L2-hot after first blocks; keeps gate-phase regs low)
  const int j32 = lane & 31, k16 = lane & 15;
  float acc = b1[j32];
  #pragma unroll
  for (int i = 0; i < NQ; ++i) acc = fmaf(feats[i], W1[i * 32 + j32], acc);
  float h1 = fast_tanh(acc);

  float acc2 = b2[k16];
  #pragma unroll
  for (int jj = 0; jj < 32; ++jj)
    acc2 = fmaf(rdlane(h1, jj), W2[jj * 16 + k16], acc2);   // readlane: 0 DS
  float h2 = fast_tanh(acc2);

  float vv = h2 * W3[k16];
  vv += dppf<0xB1>(vv);
  vv += dppf<0x4E>(vv);
  vv += dppf<0x1B>(dppf<0x141>(vv));   // xor4 via DPP chain
  vv += dppf<0x128>(vv);

  if (lane == 0) out[wv] = 0.1f * fast_tanh(0.5f * (vv + b3[0]));
}

} // namespace

extern "C" void kernel_launch(void* const* d_in, const int* in_sizes, int n_in,
                              void* d_out, int out_size, void* d_ws, size_t ws_size,
                              hipStream_t stream) {
  const float* z   = (const float*)d_in[0];
  const float* wts = (const float*)d_in[1];
  const float* W1  = (const float*)d_in[2];
  const float* b1  = (const float*)d_in[3];
  const float* W2  = (const float*)d_in[4];
  const float* b2  = (const float*)d_in[5];
  const float* W3  = (const float*)d_in[6];
  const float* b3  = (const float*)d_in[7];
  float* out = (float*)d_out;
  (void)d_ws; (void)ws_size;

  int B = in_sizes[0] / NQ;                 // 4096
  int blocks = (B + 3) / 4;                 // 4 waves per 256-thread block
  hipLaunchKernelGGL(qgan_kernel, dim3(blocks), dim3(256), 0, stream,
                     z, wts, W1, b1, W2, b2, W3, b3, out, B);
}

// Round 8
// 94.114 us; speedup vs baseline: 1.1055x; 1.1055x over previous
//
#include <hip/hip_runtime.h>

namespace {

constexpr int NQ = 10;

struct cplx { float re, im; };

__device__ __forceinline__ cplx cmul(cplx a, cplx b) {
  return cplx{ fmaf(a.re, b.re, -a.im * b.im), fmaf(a.re, b.im, a.im * b.re) };
}
// u*a + v*b (complex), 8 scalar FMA
__device__ __forceinline__ cplx cmadd2(cplx u, cplx a, cplx v, cplx b) {
  cplx r;
  r.re = fmaf(u.re, a.re, fmaf(-u.im, a.im, fmaf(v.re, b.re, -v.im * b.im)));
  r.im = fmaf(u.re, a.im, fmaf( u.im, a.re, fmaf(v.re, b.im,  v.im * b.re)));
  return r;
}
__device__ __forceinline__ cplx csel(bool c, cplx x, cplx y) {
  return cplx{ c ? x.re : y.re, c ? x.im : y.im };
}

__device__ __forceinline__ float fast_tanh(float x) {
  float xc = fminf(fmaxf(x, -10.f), 10.f);
  float e = __expf(2.f * xc);
  return __fdividef(e - 1.f, e + 1.f);
}

// ---- cross-lane primitives ----
__device__ __forceinline__ float rdlane(float v, int l) {
  return __int_as_float(__builtin_amdgcn_readlane(__float_as_int(v), l));
}
// DPP: quad_perm xor1=0xB1 xor2=0x4E xor3=0x1B; row_ror:8=0x128 (xor8);
// row_mirror=0x140 (xor15); row_half_mirror=0x141 (xor7)
template<int CTRL>
__device__ __forceinline__ float dppf(float v) {
  return __int_as_float(__builtin_amdgcn_update_dpp(0, __float_as_int(v), CTRL, 0xF, 0xF, true));
}
template<int CTRL>
__device__ __forceinline__ cplx dppc(cplx v) { return cplx{ dppf<CTRL>(v.re), dppf<CTRL>(v.im) }; }
template<int C1, int C2>
__device__ __forceinline__ cplx dppc2(cplx v) { return dppc<C2>(dppc<C1>(v)); }
template<int PAT>   // ds_swizzle BitMode: (xor<<10)|(or<<5)|and
__device__ __forceinline__ float swzf(float v) {
  return __int_as_float(__builtin_amdgcn_ds_swizzle(__float_as_int(v), PAT));
}
template<int PAT>
__device__ __forceinline__ cplx swzc(cplx v) { return cplx{ swzf<PAT>(v.re), swzf<PAT>(v.im) }; }
__device__ __forceinline__ float bperm(int addr, float v) {
  return __int_as_float(__builtin_amdgcn_ds_bpermute(addr, __float_as_int(v)));
}

// ---- per-lane Rot matrices (lane g holds gate g), broadcast by readlane ----
struct Umat { float r00,i00,r01,i01,r10,i10,r11,i11; };
__device__ __forceinline__ void getU(const Umat& m, int g,
                                     cplx& u00, cplx& u01, cplx& u10, cplx& u11) {
  u00 = cplx{rdlane(m.r00, g), rdlane(m.i00, g)};
  u01 = cplx{rdlane(m.r01, g), rdlane(m.i01, g)};
  u10 = cplx{rdlane(m.r10, g), rdlane(m.i10, g)};
  u11 = cplx{rdlane(m.r11, g), rdlane(m.i11, g)};
}

template<int HIL>
__device__ __forceinline__ void coeffs(int lane, cplx u00, cplx u01, cplx u10, cplx u11,
                                       cplx& cA, cplx& cB) {
  bool hi = (__popc(lane & HIL) & 1) != 0;
  cA = csel(hi, u11, u00); cB = csel(hi, u10, u01);
}

// ---- 2-element gate templates (all three CNOT chains algebraically folded) ----
// Gather ALL partners for both elements first (one latency window), then consume.
template<int HIL, class X>
__device__ __forceinline__ void lane_gate2(cplx (&amp)[2][16], int lane,
    cplx u00, cplx u01, cplx u10, cplx u11, X xch) {
  cplx cA, cB; coeffs<HIL>(lane, u00,u01,u10,u11, cA, cB);
  cplx o[2][16];
  #pragma unroll
  for (int e = 0; e < 2; ++e)
    #pragma unroll
    for (int t = 0; t < 16; ++t) o[e][t] = xch(amp[e][t]);
  #pragma unroll
  for (int e = 0; e < 2; ++e)
    #pragma unroll
    for (int t = 0; t < 16; ++t) amp[e][t] = cmadd2(cA, amp[e][t], cB, o[e][t]);
}

template<int LOCX, int HIL, class X>
__device__ __forceinline__ void mixed_gate2(cplx (&amp)[2][16], int lane,
    cplx u00, cplx u01, cplx u10, cplx u11, X xch) {
  cplx cA, cB; coeffs<HIL>(lane, u00,u01,u10,u11, cA, cB);
  cplx o[2][16];
  #pragma unroll
  for (int e = 0; e < 2; ++e)
    #pragma unroll
    for (int t = 0; t < 16; ++t) o[e][t] = xch(amp[e][t ^ LOCX]);
  #pragma unroll
  for (int e = 0; e < 2; ++e)
    #pragma unroll
    for (int t = 0; t < 16; ++t) amp[e][t] = cmadd2(cA, amp[e][t], cB, o[e][t]);
}

constexpr int hbit(int m) { return m >= 8 ? 8 : (m >= 4 ? 4 : (m >= 2 ? 2 : 1)); }
template<int PLOC, int HIL, int HILOC>
__device__ __forceinline__ void local_gate2(cplx (&amp)[2][16], int lane,
    cplx u00, cplx u01, cplx u10, cplx u11) {
  bool h0 = (__popc(lane & HIL) & 1) != 0;
  cplx cA0 = csel(h0, u11, u00), cB0 = csel(h0, u10, u01);
  cplx cA1 = csel(h0, u00, u11), cB1 = csel(h0, u01, u10);
  #pragma unroll
  for (int e = 0; e < 2; ++e)
    #pragma unroll
    for (int ta = 0; ta < 16; ++ta) {
      if (ta & hbit(PLOC)) continue;
      const int tb = ta ^ PLOC;
      const bool pa = (__popc(ta & HILOC) & 1) != 0;   // compile-time
      cplx aA = amp[e][ta], aB = amp[e][tb];
      if (!pa) { amp[e][ta] = cmadd2(cA0, aA, cB0, aB); amp[e][tb] = cmadd2(cA1, aB, cB1, aA); }
      else     { amp[e][ta] = cmadd2(cA1, aA, cB1, aB); amp[e][tb] = cmadd2(cA0, aB, cB0, aA); }
    }
}

// 6-stage lane-space WHT butterfly: lane L ends with sum_l v_l * (-1)^popc(l & L)
__device__ __forceinline__ float wht6(float v, float s1, float s2, float s4,
                                      float s8, float s16, float s32) {
  float o;
  o = dppf<0xB1>(v);               v = fmaf(s1,  v, o);   // xor1
  o = dppf<0x4E>(v);               v = fmaf(s2,  v, o);   // xor2
  o = dppf<0x1B>(dppf<0x141>(v));  v = fmaf(s4,  v, o);   // xor4 = xor7 o xor3
  o = dppf<0x128>(v);              v = fmaf(s8,  v, o);   // xor8
  o = swzf<0x401F>(v);             v = fmaf(s16, v, o);   // xor16 (DS swizzle)
  o = __shfl_xor(v, 32);           v = fmaf(s32, v, o);   // xor32 (DS bpermute)
  return v;
}

// (64,1): 1-wave blocks, VGPR uncapped; 2048 blocks -> 8 waves/CU (2/SIMD)
__global__ __launch_bounds__(64, 1)
void qgan_kernel(const float* __restrict__ z, const float* __restrict__ wts,
                 const float* __restrict__ W1, const float* __restrict__ b1,
                 const float* __restrict__ W2, const float* __restrict__ b2,
                 const float* __restrict__ W3, const float* __restrict__ b3,
                 float* __restrict__ out, int B)
{
  const int lane = threadIdx.x;
  const int e0   = blockIdx.x * 2;         // two batch elements per wave
  if (e0 >= B) return;

  // ---- shared MLP weights (small; prefetch under gate compute) ----
  const int j32 = lane & 31, k16 = lane & 15;
  float w1r[10];
  #pragma unroll
  for (int i = 0; i < NQ; ++i) w1r[i] = W1[i * 32 + j32];
  float b1v = b1[j32], b2v = b2[k16], w3v = W3[k16], b3v = b3[0];

  // ---- 30 Rot matrices lane-parallel (lane g -> gate g), shared by both elems ----
  Umat m;
  {
    int g = (lane < 30) ? lane : 0;
    float wa = wts[g * 3 + 0], wb = wts[g * 3 + 1], wc = wts[g * 3 + 2];
    float al = 0.5f * (wa + wc), be = 0.5f * (wa - wc), hb = 0.5f * wb;
    float ca = __cosf(al),  sa = __sinf(al);
    float cbe = __cosf(be), sbe = __sinf(be);
    float cb = __cosf(hb),  sb = __sinf(hb);
    m.r00 =  cb * ca;  m.i00 = -cb * sa;
    m.r01 = -sb * cbe; m.i01 = -sb * sbe;
    m.r10 =  sb * cbe; m.i10 = -sb * sbe;
    m.r11 =  cb * ca;  m.i11 =  cb * sa;
  }

  cplx u00, u01, u10, u11;
  const float* zp[2] = { z + e0 * NQ, z + (e0 + 1) * NQ };

  // ---- init: RY product state fused with layer-0 1q gates (identity layout) ----
  cplx amp[2][16];
  {
    cplx laneF[2] = { {1.f, 0.f}, {1.f, 0.f} };
    #pragma unroll
    for (int q = 0; q < 6; ++q) {          // wires 0..5 -> lane bits 5..0
      getU(m, q, u00, u01, u10, u11);
      #pragma unroll
      for (int e = 0; e < 2; ++e) {
        float zz = fminf(fmaxf(zp[e][q], -1.f), 1.f);
        float c0 = __cosf(0.5f * zz), s0 = __sinf(0.5f * zz);
        cplx va = { fmaf(u00.re, c0, u01.re * s0), fmaf(u00.im, c0, u01.im * s0) };
        cplx vb = { fmaf(u10.re, c0, u11.re * s0), fmaf(u10.im, c0, u11.im * s0) };
        cplx f = csel((lane >> (5 - q)) & 1, vb, va);
        laneF[e] = (q == 0) ? f : cmul(laneF[e], f);
      }
    }
    cplx va_[2][4], vb_[2][4];             // wires 6..9 -> local bits 3..0
    #pragma unroll
    for (int q = 6; q < 10; ++q) {
      getU(m, q, u00, u01, u10, u11);
      #pragma unroll
      for (int e = 0; e < 2; ++e) {
        float zz = fminf(fmaxf(zp[e][q], -1.f), 1.f);
        float c0 = __cosf(0.5f * zz), s0 = __sinf(0.5f * zz);
        va_[e][q - 6] = { fmaf(u00.re, c0, u01.re * s0), fmaf(u00.im, c0, u01.im * s0) };
        vb_[e][q - 6] = { fmaf(u10.re, c0, u11.re * s0), fmaf(u10.im, c0, u11.im * s0) };
      }
    }
    #pragma unroll
    for (int e = 0; e < 2; ++e) {
      cplx P2[4];
      P2[0] = cmul(va_[e][2], va_[e][3]);
      P2[1] = cmul(va_[e][2], vb_[e][3]);
      P2[2] = cmul(vb_[e][2], va_[e][3]);
      P2[3] = cmul(vb_[e][2], vb_[e][3]);
      cplx g0 = cmul(laneF[e], va_[e][0]);   // wire6 = bit3
      cplx g1 = cmul(laneF[e], vb_[e][0]);
      #pragma unroll
      for (int t = 0; t < 16; ++t) {
        cplx t7 = ((t >> 2) & 1) ? vb_[e][1] : va_[e][1];
        cplx tt = cmul(t7, P2[t & 3]);
        amp[e][t] = cmul(((t >> 3) & 1) ? g1 : g0, tt);
      }
    }
  }

  const int a1 = ((lane ^ 0x30) & 63) << 2;   // layer-1 b=9 bperm addr
  const int a2 = ((lane ^ 0x28) & 63) << 2;   // layer-2 b=9 bperm addr
  auto xb1  = [&](cplx v) { return cplx{ bperm(a1, v.re), bperm(a1, v.im) }; };
  auto xb2  = [&](cplx v) { return cplx{ bperm(a2, v.re), bperm(a2, v.im) }; };
  auto xs18 = [ ](cplx v) { return swzc<0x601F>(v); };   // xor 0x18
  auto xs14 = [ ](cplx v) { return swzc<0x501F>(v); };   // xor 0x14
  auto xdC  = [ ](cplx v) { return dppc2<0x140, 0x1B>(v); };  // xor 0xC
  auto xd6  = [ ](cplx v) { return dppc2<0x141, 0xB1>(v); };  // xor 6
  auto xd3  = [ ](cplx v) { return dppc<0x1B>(v); };          // xor 3
  auto xdA  = [ ](cplx v) { return dppc2<0x128, 0x4E>(v); };  // xor 0xA
  auto xd5  = [ ](cplx v) { return dppc2<0x141, 0x4E>(v); };  // xor 5
  auto xd2  = [ ](cplx v) { return dppc<0x4E>(v); };          // xor 2
  auto xd1  = [ ](cplx v) { return dppc<0xB1>(v); };          // xor 1

  // ---- Layer 1 under layout C^1 ----
  getU(m, 10, u00,u01,u10,u11); lane_gate2<0x20>(amp, lane, u00,u01,u10,u11, xb1);      // b=9
  getU(m, 11, u00,u01,u10,u11); lane_gate2<0x30>(amp, lane, u00,u01,u10,u11, xs18);     // b=8
  getU(m, 12, u00,u01,u10,u11); lane_gate2<0x38>(amp, lane, u00,u01,u10,u11, xdC);      // b=7
  getU(m, 13, u00,u01,u10,u11); lane_gate2<0x3C>(amp, lane, u00,u01,u10,u11, xd6);      // b=6
  getU(m, 14, u00,u01,u10,u11); lane_gate2<0x3E>(amp, lane, u00,u01,u10,u11, xd3);      // b=5
  getU(m, 15, u00,u01,u10,u11); mixed_gate2<8, 0x3F>(amp, lane, u00,u01,u10,u11, xd1);  // b=4
  getU(m, 16, u00,u01,u10,u11); local_gate2<0xC, 0x3F, 0x8>(amp, lane, u00,u01,u10,u11);
  getU(m, 17, u00,u01,u10,u11); local_gate2<0x6, 0x3F, 0xC>(amp, lane, u00,u01,u10,u11);
  getU(m, 18, u00,u01,u10,u11); local_gate2<0x3, 0x3F, 0xE>(amp, lane, u00,u01,u10,u11);
  getU(m, 19, u00,u01,u10,u11); local_gate2<0x1, 0x3F, 0xF>(amp, lane, u00,u01,u10,u11);

  // ---- Layer 2 under layout C^2 ----
  getU(m, 20, u00,u01,u10,u11); lane_gate2<0x20>(amp, lane, u00,u01,u10,u11, xb2);      // b=9
  getU(m, 21, u00,u01,u10,u11); lane_gate2<0x10>(amp, lane, u00,u01,u10,u11, xs14);     // b=8
  getU(m, 22, u00,u01,u10,u11); lane_gate2<0x28>(amp, lane, u00,u01,u10,u11, xdA);      // b=7
  getU(m, 23, u00,u01,u10,u11); lane_gate2<0x14>(amp, lane, u00,u01,u10,u11, xd5);      // b=6
  getU(m, 24, u00,u01,u10,u11); mixed_gate2<8, 0x2A>(amp, lane, u00,u01,u10,u11, xd2);  // b=5
  getU(m, 25, u00,u01,u10,u11); mixed_gate2<4, 0x15>(amp, lane, u00,u01,u10,u11, xd1);  // b=4
  getU(m, 26, u00,u01,u10,u11); local_gate2<0xA, 0x2A, 0x8>(amp, lane, u00,u01,u10,u11);
  getU(m, 27, u00,u01,u10,u11); local_gate2<0x5, 0x15, 0x4>(amp, lane, u00,u01,u10,u11);
  getU(m, 28, u00,u01,u10,u11); local_gate2<0x2, 0x2A, 0xA>(amp, lane, u00,u01,u10,u11);
  getU(m, 29, u00,u01,u10,u11); local_gate2<0x1, 0x15, 0x5>(amp, lane, u00,u01,u10,u11);

  // ---- measurement under layout C^3 (final chain folded into WHT masks) ----
  float s1  = (lane & 1)  ? -1.f : 1.f;
  float s2  = (lane & 2)  ? -1.f : 1.f;
  float s4  = (lane & 4)  ? -1.f : 1.f;
  float s8  = (lane & 8)  ? -1.f : 1.f;
  float s16 = (lane & 16) ? -1.f : 1.f;
  float s32 = (lane & 32) ? -1.f : 1.f;

  float feats[2][10];
  #pragma unroll
  for (int e = 0; e < 2; ++e) {
    float p[16];
    #pragma unroll
    for (int t = 0; t < 16; ++t)
      p[t] = fmaf(amp[e][t].re, amp[e][t].re, amp[e][t].im * amp[e][t].im);
    #pragma unroll
    for (int k = 1; k <= 8; k <<= 1) {     // local 4-bit WHT
      #pragma unroll
      for (int t = 0; t < 16; ++t) {
        if (t & k) continue;
        float a = p[t], b = p[t | k];
        p[t] = a + b; p[t | k] = a - b;
      }
    }
    float B0 = wht6(p[0],   s1,s2,s4,s8,s16,s32);
    float B8 = wht6(p[8],   s1,s2,s4,s8,s16,s32);
    float BC = wht6(p[0xC], s1,s2,s4,s8,s16,s32);
    float B6 = wht6(p[6],   s1,s2,s4,s8,s16,s32);
    float B3 = wht6(p[3],   s1,s2,s4,s8,s16,s32);
    feats[e][0] = rdlane(B0, 0x20); feats[e][1] = rdlane(B0, 0x30);
    feats[e][2] = rdlane(B0, 0x18); feats[e][3] = rdlane(B0, 0x0C);
    feats[e][4] = rdlane(B0, 0x26); feats[e][5] = rdlane(B0, 0x33);
    feats[e][6] = rdlane(B8, 0x19); feats[e][7] = rdlane(BC, 0x0C);
    feats[e][8] = rdlane(B6, 0x26); feats[e][9] = rdlane(B3, 0x33);
  }

  // ---- prefetch W2 after amps are dead ----
  float w2r[32];
  #pragma unroll
  for (int jj = 0; jj < 32; ++jj) w2r[jj] = W2[jj * 16 + k16];

  // ---- MLP x2: 10->32 tanh ->16 tanh ->1 ; sigmoid*0.2-0.1 == 0.1*tanh(raw/2) ----
  float r[2];
  #pragma unroll
  for (int e = 0; e < 2; ++e) {
    float acc = b1v;
    #pragma unroll
    for (int i = 0; i < NQ; ++i) acc = fmaf(feats[e][i], w1r[i], acc);
    float h1 = fast_tanh(acc);

    float acc2 = b2v;
    #pragma unroll
    for (int jj = 0; jj < 32; ++jj)
      acc2 = fmaf(rdlane(h1, jj), w2r[jj], acc2);   // readlane: 0 DS
    float h2 = fast_tanh(acc2);

    float vv = h2 * w3v;
    vv += dppf<0xB1>(vv);
    vv += dppf<0x4E>(vv);
    vv += dppf<0x1B>(dppf<0x141>(vv));   // xor4 via DPP chain
    vv += dppf<0x128>(vv);
    r[e] = 0.1f * fast_tanh(0.5f * (vv + b3v));
  }

  if (lane == 0) { out[e0] = r[0]; out[e0 + 1] = r[1]; }
}

} // namespace

extern "C" void kernel_launch(void* const* d_in, const int* in_sizes, int n_in,
                              void* d_out, int out_size, void* d_ws, size_t ws_size,
                              hipStream_t stream) {
  const float* z   = (const float*)d_in[0];
  const float* wts = (const float*)d_in[1];
  const float* W1  = (const float*)d_in[2];
  const float* b1  = (const float*)d_in[3];
  const float* W2  = (const float*)d_in[4];
  const float* b2  = (const float*)d_in[5];
  const float* W3  = (const float*)d_in[6];
  const float* b3  = (const float*)d_in[7];
  float* out = (float*)d_out;
  (void)d_ws; (void)ws_size;

  int B = in_sizes[0] / NQ;                 // 4096
  int blocks = (B + 1) / 2;                 // 2 elements per 64-thread (1-wave) block
  hipLaunchKernelGGL(qgan_kernel, dim3(blocks), dim3(64), 0, stream,
                     z, wts, W1, b1, W2, b2, W3, b3, out, B);
}